// Round 2
// baseline (6156.039 us; speedup 1.0000x reference)
//
#include <hip/hip_runtime.h>
#include <hip/hip_bf16.h>
#include <cstdint>

typedef __bf16 bf16x8 __attribute__((ext_vector_type(8)));
typedef __bf16 bf16x4v __attribute__((ext_vector_type(4)));
typedef float f32x4 __attribute__((ext_vector_type(4)));

// ---- MFMA + async-copy helpers -------------------------------------------
static __device__ __forceinline__ f32x4 mfma16(bf16x8 a, bf16x8 b, f32x4 c) {
  return __builtin_amdgcn_mfma_f32_16x16x32_bf16(a, b, c, 0, 0, 0);
}
static __device__ __forceinline__ void gld_lds16(const void* g, void* l) {
  __builtin_amdgcn_global_load_lds(
      (__attribute__((address_space(1))) void*)(uintptr_t)g,
      (__attribute__((address_space(3))) void*)l, 16, 0, 0);
}

// ---- GEMM: C(MxBN-tiles) = A(MxK) @ Bt(NxK)^T, bf16 in, fp32 accum -------
// 1-D grid = 8 * rpx * nY blocks; XCD-aware swizzle:
//   MODE 0 (col-fastest): row-tile's nY col-blocks adjacent -> same XCD,
//           concurrent -> A-tile fetched once (big-A shapes).
//   MODE 1 (row-fastest): XCD's A-slice (rpx tiles) L2-resident across the
//           whole col sweep (K=768 shapes).
// BN=128: 4 waves as 2x2, 64x64 out each (16 MFMA/K-step) — occupancy-rich
//         shapes (N>=2304).
// BN=64:  4 waves as 4x1, 32x64 out each (8 MFMA/K-step) — narrow-N shapes
//         (N=768): 2x more blocks, grid-limited occupancy recovered.
// EPI 0: bf16 store; 1: bf16 relu(acc+bias); 2: fp32 x += acc+bias;
// EPI 3: patch embed remap + patch_b + pos_emb.
template <int EPI, int MODE, int BN>
__global__ __launch_bounds__(256) void gemm_bt(
    const __bf16* __restrict__ A, const __bf16* __restrict__ Bt, int K, int ldc,
    int M, int nY,
    __bf16* __restrict__ outb, float* __restrict__ outf,
    const float* __restrict__ bias, const float* __restrict__ pos) {
  __shared__ __align__(16) __bf16 lsA[128 * 32];
  __shared__ __align__(16) __bf16 lsB[128 * 32];  // BN=64 uses first 64*32
  const int id = blockIdx.x;
  const int xcd = id & 7;
  const int j = id >> 3;
  const int rpx = (int)gridDim.x / (8 * nY);
  int bx, by;
  if (MODE == 0) { bx = xcd * rpx + j / nY; by = j % nY; }
  else           { by = j / rpx;            bx = xcd * rpx + j % rpx; }
  const long m0 = (long)bx * 128, n0 = (long)by * BN;
  if (m0 >= M) return;

  const int tid = threadIdx.x;
  const int wave = tid >> 6, lane = tid & 63;
  const int quad = lane >> 4, l16 = lane & 15;

  const int c0 = tid, c1 = 256 + tid;
  const __bf16* gA0 = A + (m0 + (c0 >> 2)) * (long)K + (c0 & 3) * 8;
  const __bf16* gA1 = A + (m0 + (c1 >> 2)) * (long)K + (c1 & 3) * 8;
  const __bf16* gB0 = Bt + (n0 + (c0 >> 2)) * (long)K + (c0 & 3) * 8;
  const __bf16* gB1 = Bt + (n0 + (c1 >> 2)) * (long)K + (c1 & 3) * 8;
  __bf16* lA0 = lsA + wave * 512;
  __bf16* lA1 = lsA + 2048 + wave * 512;
  __bf16* lB0 = lsB + wave * 512;
  __bf16* lB1 = lsB + 2048 + wave * 512;

  // wave -> output subtile
  constexpr int MF = (BN == 128) ? 4 : 2;       // 16-row m-frags per wave
  const int wr = (BN == 128) ? (wave >> 1) : wave;
  const int wc = (BN == 128) ? (wave & 1) : 0;
  constexpr int RPW = (BN == 128) ? 64 : 32;    // rows per wave
  const __bf16* rA = lsA + (wr * RPW + l16) * 32 + quad * 8;
  const __bf16* rB = lsB + (wc * 64 + l16) * 32 + quad * 8;

  const f32x4 zz = {0.f, 0.f, 0.f, 0.f};
  f32x4 acc[MF][4];
#pragma unroll
  for (int i = 0; i < MF; ++i)
#pragma unroll
    for (int jj = 0; jj < 4; ++jj) acc[i][jj] = zz;

  for (int k0 = 0; k0 < K; k0 += 32) {
    gld_lds16(gA0, lA0);
    gld_lds16(gA1, lA1);
    gld_lds16(gB0, lB0);
    if (BN == 128) gld_lds16(gB1, lB1);
    gA0 += 32; gA1 += 32; gB0 += 32;
    if (BN == 128) gB1 += 32;
    __syncthreads();
    bf16x8 af[MF], bfr[4];
#pragma unroll
    for (int mi = 0; mi < MF; ++mi) af[mi] = *(const bf16x8*)(rA + mi * 512);
#pragma unroll
    for (int ni = 0; ni < 4; ++ni) bfr[ni] = *(const bf16x8*)(rB + ni * 512);
#pragma unroll
    for (int mi = 0; mi < MF; ++mi)
#pragma unroll
      for (int ni = 0; ni < 4; ++ni)
        acc[mi][ni] = mfma16(af[mi], bfr[ni], acc[mi][ni]);
    __syncthreads();
  }

#pragma unroll
  for (int mi = 0; mi < MF; ++mi) {
#pragma unroll
    for (int r = 0; r < 4; ++r) {
      const long row = m0 + wr * RPW + mi * 16 + quad * 4 + r;
      if (EPI == 3) {
        const int rr = (int)row;
        const int gsel = rr >= 6272 ? 1 : 0;
        const int rm = rr - gsel * 6272;
        const int bb = rm / 196, pp = rm % 196;
        const int t = gsel ? (198 + pp) : (1 + pp);
        float* xr = outf + ((long)bb * 426 + t) * 768;
        const float* pr = pos + (long)t * 768;
#pragma unroll
        for (int ni = 0; ni < 4; ++ni) {
          const long col = n0 + wc * 64 + ni * 16 + l16;
          xr[col] = acc[mi][ni][r] + bias[col] + pr[col];
        }
      } else {
#pragma unroll
        for (int ni = 0; ni < 4; ++ni) {
          const long col = n0 + wc * 64 + ni * 16 + l16;
          const float v = acc[mi][ni][r];
          if (EPI == 0) outb[row * ldc + col] = (__bf16)v;
          else if (EPI == 1) outb[row * ldc + col] = (__bf16)fmaxf(v + bias[col], 0.f);
          else outf[row * ldc + col] += v + bias[col];
        }
      }
    }
  }
}

// ---- fp32 (K,N) -> bf16 (N,K) batched transpose-pack ---------------------
__global__ __launch_bounds__(256) void transpose_pack(
    const float* __restrict__ in, __bf16* __restrict__ out, int K, int N,
    int nh, long out_ls, long out_hs) {
  __shared__ float tile[32][33];
  const int z = blockIdx.z;
  const long in_o = (long)z * K * N;
  const long out_o = (long)(z / nh) * out_ls + (long)(z % nh) * out_hs;
  const int n0 = blockIdx.x * 32, k0 = blockIdx.y * 32;
  const int tx = threadIdx.x, ty = threadIdx.y;
#pragma unroll
  for (int i = 0; i < 4; ++i)
    tile[ty + i * 8][tx] = in[in_o + (long)(k0 + ty + i * 8) * N + n0 + tx];
  __syncthreads();
#pragma unroll
  for (int i = 0; i < 4; ++i)
    out[out_o + (long)(n0 + ty + i * 8) * K + k0 + tx] = (__bf16)tile[tx][ty + i * 8];
}

// ---- patch extraction: images -> bf16 patch matrix (12544 x 768) ---------
__global__ __launch_bounds__(256) void patches_k(const float* __restrict__ img0,
                                                 const float* __restrict__ img1,
                                                 __bf16* __restrict__ out) {
  const int row = blockIdx.x;
  const int gsel = row >= 6272 ? 1 : 0;
  const int rm = row - gsel * 6272;
  const int b = rm / 196, p = rm % 196;
  const int py = p / 14, px = p % 14;
  const float* img = gsel ? img1 : img0;
#pragma unroll
  for (int i = 0; i < 3; ++i) {
    const int k = threadIdx.x + i * 256;
    const int pidx = k / 3, c = k - pidx * 3;
    const int pr = pidx >> 4, pc = pidx & 15;
    const float v = img[(((long)b * 224 + py * 16 + pr) * 224 + px * 16 + pc) * 3 + c];
    out[(long)row * 768 + k] = (__bf16)v;
  }
}

// ---- cls/goal/lang token rows + pos_emb into fp32 x ----------------------
__global__ __launch_bounds__(256) void assemble_k(
    const float* __restrict__ cls_tok, const float* __restrict__ goal_tok,
    const float* __restrict__ tok_emb, const int* __restrict__ txt,
    const float* __restrict__ pos, float* __restrict__ x) {
  const int z = blockIdx.x;
  const int b = z / 34, j = z % 34;
  const int t = (j == 0) ? 0 : (j == 1) ? 197 : (392 + j);
  const float* src = (j == 0) ? cls_tok
                   : (j == 1) ? goal_tok
                              : tok_emb + (long)txt[b * 32 + (j - 2)] * 768;
  float* dst = x + ((long)b * 426 + t) * 768;
  const float* pr = pos + (long)t * 768;
#pragma unroll
  for (int i = 0; i < 3; ++i) {
    const int k = threadIdx.x + i * 256;
    dst[k] = src[k] + pr[k];
  }
}

// ---- LayerNorm fp32 -> bf16 (one wave per row) ---------------------------
// CLS=1: gather-mode — input row is blockIdx.x*426 (cls token per batch),
// output row compact. Only the 32 cls rows feed the action head.
template <int CLS>
__global__ __launch_bounds__(64) void ln_k(const float* __restrict__ x,
                                           const float* __restrict__ g,
                                           const float* __restrict__ b,
                                           __bf16* __restrict__ out) {
  const int row = blockIdx.x, lane = threadIdx.x;
  const long irow = CLS ? (long)row * 426 : (long)row;
  const float4* xr = (const float4*)(x + irow * 768);
  float4 v[3];
  float s = 0.f, q = 0.f;
#pragma unroll
  for (int i = 0; i < 3; ++i) {
    v[i] = xr[lane + i * 64];
    s += v[i].x + v[i].y + v[i].z + v[i].w;
    q += v[i].x * v[i].x + v[i].y * v[i].y + v[i].z * v[i].z + v[i].w * v[i].w;
  }
#pragma unroll
  for (int o = 32; o > 0; o >>= 1) {
    s += __shfl_xor(s, o);
    q += __shfl_xor(q, o);
  }
  const float mean = s * (1.f / 768.f);
  const float var = q * (1.f / 768.f) - mean * mean;
  const float rs = rsqrtf(var + 1e-5f);
  const float4* g4 = (const float4*)g;
  const float4* b4 = (const float4*)b;
#pragma unroll
  for (int i = 0; i < 3; ++i) {
    const float4 gg = g4[lane + i * 64], bb = b4[lane + i * 64];
    bf16x4v o4;
    o4[0] = (__bf16)((v[i].x - mean) * rs * gg.x + bb.x);
    o4[1] = (__bf16)((v[i].y - mean) * rs * gg.y + bb.y);
    o4[2] = (__bf16)((v[i].z - mean) * rs * gg.z + bb.z);
    o4[3] = (__bf16)((v[i].w - mean) * rs * gg.w + bb.w);
    *(bf16x4v*)(out + (long)row * 768 + (lane + i * 64) * 4) = o4;
  }
}

// ---- V transpose per head: qkv[:,1536+h*64+e] -> vt[bh][e][448] ----------
__global__ __launch_bounds__(256) void vtrans_k(const __bf16* __restrict__ qkv,
                                                __bf16* __restrict__ vt) {
  __shared__ __bf16 tile[64][66];
  const int bh = blockIdx.x;
  const int b = bh / 12, h = bh % 12;
  const int s0 = blockIdx.y * 64;
  const int t = threadIdx.x;
  const int sr = t >> 2, part = t & 3;
  const __bf16* src = qkv + ((long)(b * 426 + s0 + sr)) * 2304 + 1536 + h * 64 + part * 16;
#pragma unroll
  for (int j = 0; j < 16; ++j) tile[sr][part * 16 + j] = src[j];
  __syncthreads();
  __bf16* dst = vt + ((long)bh * 64 + sr) * 448 + s0 + part * 16;
#pragma unroll
  for (int j = 0; j < 16; ++j) {
    const int s = s0 + part * 16 + j;
    dst[j] = (s < 426) ? tile[part * 16 + j][sr] : (__bf16)0.f;
  }
}

// ---- flash attention: 4 waves/WG, 64-query tile, 64-key chunks -----------
__global__ __launch_bounds__(256) void attn_k(const __bf16* __restrict__ qkv,
                                              const __bf16* __restrict__ vt,
                                              __bf16* __restrict__ attout) {
  __shared__ __align__(16) __bf16 lds[8192 + 4096];  // K(4096) | V(4096) | P(4096)
  const int tid = threadIdx.x;
  const int wave = tid >> 6, lane = tid & 63;
  const int quad = lane >> 4, l16 = lane & 15;
  const int bh = blockIdx.x;
  const int b = bh / 12, h = bh % 12;
  const int q0 = blockIdx.y * 64 + wave * 16;
  const long b426 = (long)b * 426;

  const int swz0 = ((quad) ^ (l16 & 7)) * 8;
  const int swz1 = ((4 + quad) ^ (l16 & 7)) * 8;
  __bf16* lsK = lds;
  __bf16* lsV = lds + 4096;
  __bf16* lsP = lds + 8192 + wave * 1024;

  const __bf16* gsrc[4];
  long gstep[4];
#pragma unroll
  for (int s = 0; s < 4; ++s) {
    const int c = s * 256 + tid;
    if (c < 512) {
      const int key = c >> 3, part = (c & 7) ^ (key & 7);
      gsrc[s] = qkv + (b426 + key) * 2304 + 768 + h * 64 + part * 8;
      gstep[s] = 64 * 2304;
    } else {
      const int cv = c - 512;
      const int e = cv >> 3, part = (cv & 7) ^ (e & 7);
      gsrc[s] = vt + ((long)bh * 64 + e) * 448 + part * 8;
      gstep[s] = 64;
    }
  }
  __bf16* ldst[4];
#pragma unroll
  for (int s = 0; s < 4; ++s) ldst[s] = lds + (s * 256 + (tid & ~63)) * 8;

  const long qrow = (b426 + q0 + l16) * 2304 + h * 64;
  const bf16x8 aq0 = *(const bf16x8*)(qkv + qrow + quad * 8);
  const bf16x8 aq1 = *(const bf16x8*)(qkv + qrow + 32 + quad * 8);

  const f32x4 zz = {0.f, 0.f, 0.f, 0.f};
  f32x4 o[4] = {zz, zz, zz, zz};
  float m_i[4] = {-3e38f, -3e38f, -3e38f, -3e38f};
  float l_i[4] = {0.f, 0.f, 0.f, 0.f};
  const float scale = 0.03608439182435161f;  // 768^-0.5

  for (int kc = 0; kc < 7; ++kc) {
    const int kbase = kc * 64;
    __syncthreads();
#pragma unroll
    for (int s = 0; s < 4; ++s) {
      gld_lds16(gsrc[s], ldst[s]);
      gsrc[s] += gstep[s];
    }
    __syncthreads();

    f32x4 s4[4] = {zz, zz, zz, zz};
#pragma unroll
    for (int nt = 0; nt < 4; ++nt) {
      const __bf16* kb = lsK + (nt * 16 + l16) * 64;
      s4[nt] = mfma16(aq0, *(const bf16x8*)(kb + swz0), s4[nt]);
      s4[nt] = mfma16(aq1, *(const bf16x8*)(kb + swz1), s4[nt]);
    }

    const int lim = 426 - kbase - l16;
#pragma unroll
    for (int r = 0; r < 4; ++r) {
      float a0 = (0 < lim)  ? s4[0][r] * scale : -1e30f;
      float a1 = (16 < lim) ? s4[1][r] * scale : -1e30f;
      float a2 = (32 < lim) ? s4[2][r] * scale : -1e30f;
      float a3 = (48 < lim) ? s4[3][r] * scale : -1e30f;
      float mx = fmaxf(fmaxf(a0, a1), fmaxf(a2, a3));
#pragma unroll
      for (int w = 1; w < 16; w <<= 1) mx = fmaxf(mx, __shfl_xor(mx, w, 16));
      mx = fmaxf(mx, m_i[r]);
      const float alpha = __expf(m_i[r] - mx);
      m_i[r] = mx;
      const float p0 = __expf(a0 - mx), p1 = __expf(a1 - mx);
      const float p2 = __expf(a2 - mx), p3 = __expf(a3 - mx);
      float rs = (p0 + p1) + (p2 + p3);
#pragma unroll
      for (int w = 1; w < 16; w <<= 1) rs += __shfl_xor(rs, w, 16);
      l_i[r] = l_i[r] * alpha + rs;
      o[0][r] *= alpha; o[1][r] *= alpha; o[2][r] *= alpha; o[3][r] *= alpha;
      const int rowb = quad * 4 + r;
      __bf16* pb = lsP + rowb * 64 + (l16 & 7);
      const int l8 = l16 >> 3, rx = rowb & 7;
      pb[((0 + l8) ^ rx) * 8] = (__bf16)p0;
      pb[((2 + l8) ^ rx) * 8] = (__bf16)p1;
      pb[((4 + l8) ^ rx) * 8] = (__bf16)p2;
      pb[((6 + l8) ^ rx) * 8] = (__bf16)p3;
    }

    const bf16x8 pa0 = *(const bf16x8*)(lsP + l16 * 64 + swz0);
    const bf16x8 pa1 = *(const bf16x8*)(lsP + l16 * 64 + swz1);
#pragma unroll
    for (int et = 0; et < 4; ++et) {
      const __bf16* vb = lsV + (et * 16 + l16) * 64;
      o[et] = mfma16(pa0, *(const bf16x8*)(vb + swz0), o[et]);
      o[et] = mfma16(pa1, *(const bf16x8*)(vb + swz1), o[et]);
    }
  }

#pragma unroll
  for (int r = 0; r < 4; ++r) {
    const int q = q0 + quad * 4 + r;
    if (q < 426) {
      const float inv = 1.f / l_i[r];
      __bf16* dst = attout + (b426 + q) * 768 + h * 64 + l16;
#pragma unroll
      for (int et = 0; et < 4; ++et) dst[et * 16] = (__bf16)(o[et][r] * inv);
    }
  }
}

// ---- action head ---------------------------------------------------------
__global__ __launch_bounds__(256) void head1_k(const __bf16* __restrict__ cls,
                                               const float* __restrict__ W1,
                                               const float* __restrict__ b1,
                                               float* __restrict__ hh) {
  __shared__ float red[4][64];
  const int blk = blockIdx.x;
  const int r = blk / 48, nt = blk % 48;
  const int tid = threadIdx.x;
  const int kq = tid >> 6, nl = tid & 63;
  const int n = nt * 64 + nl;
  const __bf16* c = cls + (long)r * 768 + kq * 192;
  const float* w = W1 + (long)(kq * 192) * 3072 + n;
  float s = 0.f;
#pragma unroll 4
  for (int k = 0; k < 192; ++k) s += (float)c[k] * w[(long)k * 3072];
  if (kq) red[kq][nl] = s;
  __syncthreads();
  if (kq == 0) {
    s += red[1][nl] + red[2][nl] + red[3][nl];
    hh[(long)r * 3072 + n] = fmaxf(s + b1[n], 0.f);
  }
}

__global__ __launch_bounds__(64) void head2_k(const float* __restrict__ hh,
                                              const float* __restrict__ W2,
                                              const float* __restrict__ b2,
                                              float* __restrict__ out) {
  const int o = blockIdx.x;
  const int r = o / 7, n = o % 7;
  const int lane = threadIdx.x;
  const float* hr = hh + (long)r * 3072;
  float s = 0.f;
  for (int k = lane; k < 3072; k += 64) s += hr[k] * W2[(long)k * 7 + n];
#pragma unroll
  for (int off = 32; off > 0; off >>= 1) s += __shfl_xor(s, off);
  if (lane == 0) out[o] = s + b2[n];
}

// ---- driver --------------------------------------------------------------
extern "C" void kernel_launch(void* const* d_in, const int* in_sizes, int n_in,
                              void* d_out, int out_size, void* d_ws, size_t ws_size,
                              hipStream_t stream) {
  (void)in_sizes; (void)n_in; (void)out_size; (void)ws_size;
  const float* images   = (const float*)d_in[0];
  const float* goal_img = (const float*)d_in[1];
  const int*   txt      = (const int*)d_in[2];
  const float* patch_W  = (const float*)d_in[3];
  const float* patch_b  = (const float*)d_in[4];
  const float* tok_emb  = (const float*)d_in[5];
  const float* pos_emb  = (const float*)d_in[6];
  const float* cls_tok  = (const float*)d_in[7];
  const float* goal_tok = (const float*)d_in[8];
  const float* Wq   = (const float*)d_in[9];
  const float* Wk   = (const float*)d_in[10];
  const float* Wv   = (const float*)d_in[11];
  const float* Wo   = (const float*)d_in[12];
  const float* bo   = (const float*)d_in[13];
  const float* ln1g = (const float*)d_in[14];
  const float* ln1b = (const float*)d_in[15];
  const float* ln2g = (const float*)d_in[16];
  const float* ln2b = (const float*)d_in[17];
  const float* W1   = (const float*)d_in[18];
  const float* b1   = (const float*)d_in[19];
  const float* W2   = (const float*)d_in[20];
  const float* b2   = (const float*)d_in[21];
  const float* lnfg = (const float*)d_in[22];
  const float* lnfb = (const float*)d_in[23];
  const float* aW1  = (const float*)d_in[24];
  const float* ab1  = (const float*)d_in[25];
  const float* aW2  = (const float*)d_in[26];
  const float* ab2  = (const float*)d_in[27];

  char* base = (char*)d_ws;
  size_t off = 0;
  auto take = [&](size_t bytes) -> char* {
    char* p = base + off;
    off += (bytes + 255) & ~(size_t)255;
    return p;
  };
  float*  x     = (float*) take((size_t)13696 * 768 * 4);
  __bf16* xn    = (__bf16*)take((size_t)13696 * 768 * 2);
  __bf16* shard = (__bf16*)take((size_t)13696 * 3072 * 2);  // patches|qkv|hbuf
  __bf16* attb  = (__bf16*)take((size_t)13696 * 768 * 2);
  __bf16* vt    = (__bf16*)take((size_t)384 * 64 * 448 * 2);
  float*  hh    = (float*) take((size_t)32 * 3072 * 4);
  __bf16* wqkv  = (__bf16*)take((size_t)12 * 2304 * 768 * 2);
  __bf16* wot   = (__bf16*)take((size_t)12 * 768 * 768 * 2);
  __bf16* w1t   = (__bf16*)take((size_t)12 * 768 * 3072 * 2);
  __bf16* w2t   = (__bf16*)take((size_t)12 * 768 * 3072 * 2);
  __bf16* pwt   = (__bf16*)take((size_t)768 * 768 * 2);
  __bf16* qkv   = shard;
  __bf16* hbuf  = shard;
  __bf16* patches = shard;

  const dim3 tpb(32, 8);
  transpose_pack<<<dim3(24, 24, 1), tpb, 0, stream>>>(patch_W, pwt, 768, 768, 1, 0L, 0L);
  transpose_pack<<<dim3(2, 24, 144), tpb, 0, stream>>>(Wq, wqkv, 768, 64, 12, 1769472L, 49152L);
  transpose_pack<<<dim3(2, 24, 144), tpb, 0, stream>>>(Wk, wqkv + 589824, 768, 64, 12, 1769472L, 49152L);
  transpose_pack<<<dim3(2, 24, 144), tpb, 0, stream>>>(Wv, wqkv + 1179648, 768, 64, 12, 1769472L, 49152L);
  transpose_pack<<<dim3(24, 24, 12), tpb, 0, stream>>>(Wo, wot, 768, 768, 1, 589824L, 0L);
  transpose_pack<<<dim3(96, 24, 12), tpb, 0, stream>>>(W1, w1t, 768, 3072, 1, 2359296L, 0L);
  transpose_pack<<<dim3(24, 96, 12), tpb, 0, stream>>>(W2, w2t, 3072, 768, 1, 2359296L, 0L);

  patches_k<<<12544, 256, 0, stream>>>(images, goal_img, patches);
  assemble_k<<<1088, 256, 0, stream>>>(cls_tok, goal_tok, tok_emb, txt, pos_emb, x);
  // grids: 8 XCD-slots * rpx rows * nY cols (rows padded to mult of 8)
  gemm_bt<3, 1, 64><<<8 * 13 * 12, 256, 0, stream>>>(patches, pwt, 768, 768, 12544, 12,
                                                     nullptr, x, patch_b, pos_emb);

  for (int l = 0; l < 12; ++l) {
    ln_k<0><<<13696, 64, 0, stream>>>(x, ln1g + l * 768, ln1b + l * 768, xn);
    gemm_bt<0, 1, 128><<<8 * 14 * 18, 256, 0, stream>>>(xn, wqkv + (long)l * 1769472, 768, 2304,
                                                        13696, 18, qkv, nullptr, nullptr, nullptr);
    vtrans_k<<<dim3(384, 7), 256, 0, stream>>>(qkv, vt);
    attn_k<<<dim3(384, 7), 256, 0, stream>>>(qkv, vt, attb);
    gemm_bt<2, 1, 64><<<8 * 14 * 12, 256, 0, stream>>>(attb, wot + (long)l * 589824, 768, 768,
                                                       13696, 12, nullptr, x, bo + l * 768, nullptr);
    ln_k<0><<<13696, 64, 0, stream>>>(x, ln2g + l * 768, ln2b + l * 768, xn);
    gemm_bt<1, 1, 128><<<8 * 14 * 24, 256, 0, stream>>>(xn, w1t + (long)l * 2359296, 768, 3072,
                                                        13696, 24, hbuf, nullptr, b1 + l * 3072, nullptr);
    gemm_bt<2, 0, 64><<<8 * 14 * 12, 256, 0, stream>>>(hbuf, w2t + (long)l * 2359296, 3072, 768,
                                                       13696, 12, nullptr, x, b2 + l * 768, nullptr);
  }
  // Final LN: only the 32 cls rows feed the action head.
  ln_k<1><<<32, 64, 0, stream>>>(x, lnfg, lnfb, xn);
  head1_k<<<1536, 256, 0, stream>>>(xn, aW1, ab1, hh);
  head2_k<<<224, 64, 0, stream>>>(hh, aW2, ab2, (float*)d_out);
}

// Round 3
// 5588.491 us; speedup vs baseline: 1.1016x; 1.1016x over previous
//
#include <hip/hip_runtime.h>
#include <hip/hip_bf16.h>
#include <cstdint>

typedef __bf16 bf16x8 __attribute__((ext_vector_type(8)));
typedef __bf16 bf16x4v __attribute__((ext_vector_type(4)));
typedef float f32x4 __attribute__((ext_vector_type(4)));

// ---- MFMA + async-copy helpers -------------------------------------------
static __device__ __forceinline__ f32x4 mfma16(bf16x8 a, bf16x8 b, f32x4 c) {
  return __builtin_amdgcn_mfma_f32_16x16x32_bf16(a, b, c, 0, 0, 0);
}
static __device__ __forceinline__ void gld_lds16(const void* g, void* l) {
  __builtin_amdgcn_global_load_lds(
      (__attribute__((address_space(1))) void*)(uintptr_t)g,
      (__attribute__((address_space(3))) void*)l, 16, 0, 0);
}

// ---- GEMM 256x256, BK=32, 8 waves (2M x 4N), 4-deep LDS ring -------------
// C(MxN) = A(MxK) @ Bt(NxK)^T, bf16 in, fp32 accum.
// Pipeline: phase t computes K-step t from buf[t%4] while staging K-step t+3
// into buf[(t+3)%4] (always a distinct buffer; its last reader finished
// before the barrier ending phase t-1 -> race-free by construction).
// One barrier per K-step; counted s_waitcnt vmcnt(8) (2 tiles in flight),
// vmcnt(4)/vmcnt(0) only in the 2-step tail. setprio(1) around MFMA cluster.
// LDS bank swizzle: 16B chunk c of row r stored at position c ^ ((r>>1)&3)
// (applied on the per-lane GLOBAL source of global_load_lds, since the LDS
// dest is hardware-linear); fragment reads apply the same XOR -> 2-way
// aliasing only (free).
// EPI 0: bf16 store; 1: bf16 relu(acc+bias); 2: fp32 x += acc+bias;
// EPI 3: patch embed remap + patch_b + pos_emb.
// MODE 0: col-fastest within XCD chunk; MODE 1: row-fastest.
template <int EPI, int MODE>
__global__ __launch_bounds__(512, 2) void gemm256(
    const __bf16* __restrict__ A, const __bf16* __restrict__ Bt, int K, int ldc,
    int M, int nY,
    __bf16* __restrict__ outb, float* __restrict__ outf,
    const float* __restrict__ bias, const float* __restrict__ pos) {
  __shared__ __align__(16) __bf16 lds[4 * 16384];  // 4 bufs x (A 16KB | B 16KB)
  const int id = blockIdx.x;
  const int xcd = id & 7;
  const int j = id >> 3;
  const int rpx = (int)gridDim.x / (8 * nY);
  int bx, by;
  if (MODE == 0) { bx = xcd * rpx + j / nY; by = j % nY; }
  else           { by = j / rpx;            bx = xcd * rpx + j % rpx; }
  const long m0 = (long)bx * 256, n0 = (long)by * 256;
  if (m0 >= M) return;

  const int tid = threadIdx.x;
  const int wave = tid >> 6, lane = tid & 63;
  const int quad = lane >> 4, l16 = lane & 15;
  const int wm = wave >> 2, wn = wave & 3;  // 2x4 wave grid, 128x64 out each

  // ---- staging (per thread): lane l of wave w writes LDS base + l*16B
  //      -> row w*16 + (l>>2), chunk-pos l&3. Fetch global chunk
  //      (l&3) ^ ((row>>1)&3) = (l&3) ^ ((l>>3)&3) so that LDS pos p of
  //      row r holds global chunk p ^ ((r>>1)&3).
  const int gc = ((lane & 3) ^ ((lane >> 3) & 3)) * 8;
  const int srow = wave * 16 + (lane >> 2);
  const __bf16* gA0 = A + (m0 + srow) * (long)K + gc;
  const __bf16* gA1 = A + (m0 + 128 + srow) * (long)K + gc;
  const __bf16* gB0 = Bt + (n0 + srow) * (long)K + gc;
  const __bf16* gB1 = Bt + (n0 + 128 + srow) * (long)K + gc;
  const int ldw = wave * 1024;  // byte offset of this wave's 16-row slice

  // ---- fragment read offsets (elements). Row stride 32 elems (64B).
  //      Want global chunk `quad` of row (base16 + l16): read swizzled pos
  //      quad ^ ((l16>>1)&3).
  const int swz = (quad ^ ((l16 >> 1) & 3)) * 8;
  const int aoff = (wm * 128 + l16) * 32 + swz;        // + mf*512
  const int boff = 8192 + (wn * 64 + l16) * 32 + swz;  // + nf*512

  const f32x4 zz = {0.f, 0.f, 0.f, 0.f};
  f32x4 acc[8][4];
#pragma unroll
  for (int i = 0; i < 8; ++i)
#pragma unroll
    for (int jj = 0; jj < 4; ++jj) acc[i][jj] = zz;

  const int NT = K >> 5;  // K-steps of 32

  auto stage = [&](int tt) {
    char* bb = (char*)lds + (tt & 3) * 32768 + ldw;
    const long ko = (long)tt * 32;
    gld_lds16(gA0 + ko, bb);
    gld_lds16(gA1 + ko, bb + 8192);
    gld_lds16(gB0 + ko, bb + 16384);
    gld_lds16(gB1 + ko, bb + 24576);
  };

  // prologue: stage tiles 0..2; ensure tile 0 resident (8 = 2 tiles in flight)
  stage(0); stage(1); stage(2);
  asm volatile("s_waitcnt vmcnt(8)\n\ts_barrier" ::: "memory");

  for (int t = 0; t < NT; ++t) {
    if (t + 3 < NT) stage(t + 3);
    const __bf16* bb = lds + (t & 3) * 16384;
    bf16x8 af[8], bf[4];
#pragma unroll
    for (int mf = 0; mf < 8; ++mf) af[mf] = *(const bf16x8*)(bb + aoff + mf * 512);
#pragma unroll
    for (int nf = 0; nf < 4; ++nf) bf[nf] = *(const bf16x8*)(bb + boff + nf * 512);
    __builtin_amdgcn_s_setprio(1);
#pragma unroll
    for (int mf = 0; mf < 8; ++mf)
#pragma unroll
      for (int nf = 0; nf < 4; ++nf)
        acc[mf][nf] = mfma16(af[mf], bf[nf], acc[mf][nf]);
    __builtin_amdgcn_s_setprio(0);
    if (t + 1 < NT) {
      // need tile t+1 resident past this barrier; leave newer tiles in flight
      if (t + 4 <= NT)      asm volatile("s_waitcnt vmcnt(8)\n\ts_barrier" ::: "memory");
      else if (t + 3 == NT) asm volatile("s_waitcnt vmcnt(4)\n\ts_barrier" ::: "memory");
      else                  asm volatile("s_waitcnt vmcnt(0)\n\ts_barrier" ::: "memory");
    }
  }

#pragma unroll
  for (int mf = 0; mf < 8; ++mf) {
#pragma unroll
    for (int r = 0; r < 4; ++r) {
      const long row = m0 + wm * 128 + mf * 16 + quad * 4 + r;
      if (row >= M) continue;
      if (EPI == 3) {
        const int rr = (int)row;
        const int gsel = rr >= 6272 ? 1 : 0;
        const int rm = rr - gsel * 6272;
        const int bb2 = rm / 196, pp = rm % 196;
        const int tpos = gsel ? (198 + pp) : (1 + pp);
        float* xr = outf + ((long)bb2 * 426 + tpos) * 768;
        const float* pr = pos + (long)tpos * 768;
#pragma unroll
        for (int nf = 0; nf < 4; ++nf) {
          const long col = n0 + wn * 64 + nf * 16 + l16;
          xr[col] = acc[mf][nf][r] + bias[col] + pr[col];
        }
      } else {
#pragma unroll
        for (int nf = 0; nf < 4; ++nf) {
          const long col = n0 + wn * 64 + nf * 16 + l16;
          const float v = acc[mf][nf][r];
          if (EPI == 0) outb[row * ldc + col] = (__bf16)v;
          else if (EPI == 1) outb[row * ldc + col] = (__bf16)fmaxf(v + bias[col], 0.f);
          else outf[row * ldc + col] += v + bias[col];
        }
      }
    }
  }
}

// ---- fp32 (K,N) -> bf16 (N,K) batched transpose-pack ---------------------
__global__ __launch_bounds__(256) void transpose_pack(
    const float* __restrict__ in, __bf16* __restrict__ out, int K, int N,
    int nh, long out_ls, long out_hs) {
  __shared__ float tile[32][33];
  const int z = blockIdx.z;
  const long in_o = (long)z * K * N;
  const long out_o = (long)(z / nh) * out_ls + (long)(z % nh) * out_hs;
  const int n0 = blockIdx.x * 32, k0 = blockIdx.y * 32;
  const int tx = threadIdx.x, ty = threadIdx.y;
#pragma unroll
  for (int i = 0; i < 4; ++i)
    tile[ty + i * 8][tx] = in[in_o + (long)(k0 + ty + i * 8) * N + n0 + tx];
  __syncthreads();
#pragma unroll
  for (int i = 0; i < 4; ++i)
    out[out_o + (long)(n0 + ty + i * 8) * K + k0 + tx] = (__bf16)tile[tx][ty + i * 8];
}

// ---- patch extraction: images -> bf16 patch matrix (12544 x 768) ---------
__global__ __launch_bounds__(256) void patches_k(const float* __restrict__ img0,
                                                 const float* __restrict__ img1,
                                                 __bf16* __restrict__ out) {
  const int row = blockIdx.x;
  const int gsel = row >= 6272 ? 1 : 0;
  const int rm = row - gsel * 6272;
  const int b = rm / 196, p = rm % 196;
  const int py = p / 14, px = p % 14;
  const float* img = gsel ? img1 : img0;
#pragma unroll
  for (int i = 0; i < 3; ++i) {
    const int k = threadIdx.x + i * 256;
    const int pidx = k / 3, c = k - pidx * 3;
    const int pr = pidx >> 4, pc = pidx & 15;
    const float v = img[(((long)b * 224 + py * 16 + pr) * 224 + px * 16 + pc) * 3 + c];
    out[(long)row * 768 + k] = (__bf16)v;
  }
}

// ---- cls/goal/lang token rows + pos_emb into fp32 x ----------------------
__global__ __launch_bounds__(256) void assemble_k(
    const float* __restrict__ cls_tok, const float* __restrict__ goal_tok,
    const float* __restrict__ tok_emb, const int* __restrict__ txt,
    const float* __restrict__ pos, float* __restrict__ x) {
  const int z = blockIdx.x;
  const int b = z / 34, j = z % 34;
  const int t = (j == 0) ? 0 : (j == 1) ? 197 : (392 + j);
  const float* src = (j == 0) ? cls_tok
                   : (j == 1) ? goal_tok
                              : tok_emb + (long)txt[b * 32 + (j - 2)] * 768;
  float* dst = x + ((long)b * 426 + t) * 768;
  const float* pr = pos + (long)t * 768;
#pragma unroll
  for (int i = 0; i < 3; ++i) {
    const int k = threadIdx.x + i * 256;
    dst[k] = src[k] + pr[k];
  }
}

// ---- LayerNorm fp32 -> bf16 (one wave per row) ---------------------------
// CLS=1: gather-mode — input row blockIdx.x*426 (cls token per batch),
// output row compact. Only the 32 cls rows feed the action head.
template <int CLS>
__global__ __launch_bounds__(64) void ln_k(const float* __restrict__ x,
                                           const float* __restrict__ g,
                                           const float* __restrict__ b,
                                           __bf16* __restrict__ out) {
  const int row = blockIdx.x, lane = threadIdx.x;
  const long irow = CLS ? (long)row * 426 : (long)row;
  const float4* xr = (const float4*)(x + irow * 768);
  float4 v[3];
  float s = 0.f, q = 0.f;
#pragma unroll
  for (int i = 0; i < 3; ++i) {
    v[i] = xr[lane + i * 64];
    s += v[i].x + v[i].y + v[i].z + v[i].w;
    q += v[i].x * v[i].x + v[i].y * v[i].y + v[i].z * v[i].z + v[i].w * v[i].w;
  }
#pragma unroll
  for (int o = 32; o > 0; o >>= 1) {
    s += __shfl_xor(s, o);
    q += __shfl_xor(q, o);
  }
  const float mean = s * (1.f / 768.f);
  const float var = q * (1.f / 768.f) - mean * mean;
  const float rs = rsqrtf(var + 1e-5f);
  const float4* g4 = (const float4*)g;
  const float4* b4 = (const float4*)b;
#pragma unroll
  for (int i = 0; i < 3; ++i) {
    const float4 gg = g4[lane + i * 64], bb = b4[lane + i * 64];
    bf16x4v o4;
    o4[0] = (__bf16)((v[i].x - mean) * rs * gg.x + bb.x);
    o4[1] = (__bf16)((v[i].y - mean) * rs * gg.y + bb.y);
    o4[2] = (__bf16)((v[i].z - mean) * rs * gg.z + bb.z);
    o4[3] = (__bf16)((v[i].w - mean) * rs * gg.w + bb.w);
    *(bf16x4v*)(out + (long)row * 768 + (lane + i * 64) * 4) = o4;
  }
}

// ---- V transpose per head: qkv[:,1536+h*64+e] -> vt[bh][e][448] ----------
__global__ __launch_bounds__(256) void vtrans_k(const __bf16* __restrict__ qkv,
                                                __bf16* __restrict__ vt) {
  __shared__ __bf16 tile[64][66];
  const int bh = blockIdx.x;
  const int b = bh / 12, h = bh % 12;
  const int s0 = blockIdx.y * 64;
  const int t = threadIdx.x;
  const int sr = t >> 2, part = t & 3;
  const __bf16* src = qkv + ((long)(b * 426 + s0 + sr)) * 2304 + 1536 + h * 64 + part * 16;
#pragma unroll
  for (int j = 0; j < 16; ++j) tile[sr][part * 16 + j] = src[j];
  __syncthreads();
  __bf16* dst = vt + ((long)bh * 64 + sr) * 448 + s0 + part * 16;
#pragma unroll
  for (int j = 0; j < 16; ++j) {
    const int s = s0 + part * 16 + j;
    dst[j] = (s < 426) ? tile[part * 16 + j][sr] : (__bf16)0.f;
  }
}

// ---- flash attention: 4 waves/WG, 64-query tile, 64-key chunks -----------
__global__ __launch_bounds__(256) void attn_k(const __bf16* __restrict__ qkv,
                                              const __bf16* __restrict__ vt,
                                              __bf16* __restrict__ attout) {
  __shared__ __align__(16) __bf16 lds[8192 + 4096];  // K(4096) | V(4096) | P(4096)
  const int tid = threadIdx.x;
  const int wave = tid >> 6, lane = tid & 63;
  const int quad = lane >> 4, l16 = lane & 15;
  const int bh = blockIdx.x;
  const int b = bh / 12, h = bh % 12;
  const int q0 = blockIdx.y * 64 + wave * 16;
  const long b426 = (long)b * 426;

  const int swz0 = ((quad) ^ (l16 & 7)) * 8;
  const int swz1 = ((4 + quad) ^ (l16 & 7)) * 8;
  __bf16* lsK = lds;
  __bf16* lsV = lds + 4096;
  __bf16* lsP = lds + 8192 + wave * 1024;

  const __bf16* gsrc[4];
  long gstep[4];
#pragma unroll
  for (int s = 0; s < 4; ++s) {
    const int c = s * 256 + tid;
    if (c < 512) {
      const int key = c >> 3, part = (c & 7) ^ (key & 7);
      gsrc[s] = qkv + (b426 + key) * 2304 + 768 + h * 64 + part * 8;
      gstep[s] = 64 * 2304;
    } else {
      const int cv = c - 512;
      const int e = cv >> 3, part = (cv & 7) ^ (e & 7);
      gsrc[s] = vt + ((long)bh * 64 + e) * 448 + part * 8;
      gstep[s] = 64;
    }
  }
  __bf16* ldst[4];
#pragma unroll
  for (int s = 0; s < 4; ++s) ldst[s] = lds + (s * 256 + (tid & ~63)) * 8;

  const long qrow = (b426 + q0 + l16) * 2304 + h * 64;
  const bf16x8 aq0 = *(const bf16x8*)(qkv + qrow + quad * 8);
  const bf16x8 aq1 = *(const bf16x8*)(qkv + qrow + 32 + quad * 8);

  const f32x4 zz = {0.f, 0.f, 0.f, 0.f};
  f32x4 o[4] = {zz, zz, zz, zz};
  float m_i[4] = {-3e38f, -3e38f, -3e38f, -3e38f};
  float l_i[4] = {0.f, 0.f, 0.f, 0.f};
  const float scale = 0.03608439182435161f;  // 768^-0.5

  for (int kc = 0; kc < 7; ++kc) {
    const int kbase = kc * 64;
    __syncthreads();
#pragma unroll
    for (int s = 0; s < 4; ++s) {
      gld_lds16(gsrc[s], ldst[s]);
      gsrc[s] += gstep[s];
    }
    __syncthreads();

    f32x4 s4[4] = {zz, zz, zz, zz};
#pragma unroll
    for (int nt = 0; nt < 4; ++nt) {
      const __bf16* kb = lsK + (nt * 16 + l16) * 64;
      s4[nt] = mfma16(aq0, *(const bf16x8*)(kb + swz0), s4[nt]);
      s4[nt] = mfma16(aq1, *(const bf16x8*)(kb + swz1), s4[nt]);
    }

    const int lim = 426 - kbase - l16;
#pragma unroll
    for (int r = 0; r < 4; ++r) {
      float a0 = (0 < lim)  ? s4[0][r] * scale : -1e30f;
      float a1 = (16 < lim) ? s4[1][r] * scale : -1e30f;
      float a2 = (32 < lim) ? s4[2][r] * scale : -1e30f;
      float a3 = (48 < lim) ? s4[3][r] * scale : -1e30f;
      float mx = fmaxf(fmaxf(a0, a1), fmaxf(a2, a3));
#pragma unroll
      for (int w = 1; w < 16; w <<= 1) mx = fmaxf(mx, __shfl_xor(mx, w, 16));
      mx = fmaxf(mx, m_i[r]);
      const float alpha = __expf(m_i[r] - mx);
      m_i[r] = mx;
      const float p0 = __expf(a0 - mx), p1 = __expf(a1 - mx);
      const float p2 = __expf(a2 - mx), p3 = __expf(a3 - mx);
      float rs = (p0 + p1) + (p2 + p3);
#pragma unroll
      for (int w = 1; w < 16; w <<= 1) rs += __shfl_xor(rs, w, 16);
      l_i[r] = l_i[r] * alpha + rs;
      o[0][r] *= alpha; o[1][r] *= alpha; o[2][r] *= alpha; o[3][r] *= alpha;
      const int rowb = quad * 4 + r;
      __bf16* pb = lsP + rowb * 64 + (l16 & 7);
      const int l8 = l16 >> 3, rx = rowb & 7;
      pb[((0 + l8) ^ rx) * 8] = (__bf16)p0;
      pb[((2 + l8) ^ rx) * 8] = (__bf16)p1;
      pb[((4 + l8) ^ rx) * 8] = (__bf16)p2;
      pb[((6 + l8) ^ rx) * 8] = (__bf16)p3;
    }

    const bf16x8 pa0 = *(const bf16x8*)(lsP + l16 * 64 + swz0);
    const bf16x8 pa1 = *(const bf16x8*)(lsP + l16 * 64 + swz1);
#pragma unroll
    for (int et = 0; et < 4; ++et) {
      const __bf16* vb = lsV + (et * 16 + l16) * 64;
      o[et] = mfma16(pa0, *(const bf16x8*)(vb + swz0), o[et]);
      o[et] = mfma16(pa1, *(const bf16x8*)(vb + swz1), o[et]);
    }
  }

#pragma unroll
  for (int r = 0; r < 4; ++r) {
    const int q = q0 + quad * 4 + r;
    if (q < 426) {
      const float inv = 1.f / l_i[r];
      __bf16* dst = attout + (b426 + q) * 768 + h * 64 + l16;
#pragma unroll
      for (int et = 0; et < 4; ++et) dst[et * 16] = (__bf16)(o[et][r] * inv);
    }
  }
}

// ---- action head ---------------------------------------------------------
__global__ __launch_bounds__(256) void head1_k(const __bf16* __restrict__ cls,
                                               const float* __restrict__ W1,
                                               const float* __restrict__ b1,
                                               float* __restrict__ hh) {
  __shared__ float red[4][64];
  const int blk = blockIdx.x;
  const int r = blk / 48, nt = blk % 48;
  const int tid = threadIdx.x;
  const int kq = tid >> 6, nl = tid & 63;
  const int n = nt * 64 + nl;
  const __bf16* c = cls + (long)r * 768 + kq * 192;
  const float* w = W1 + (long)(kq * 192) * 3072 + n;
  float s = 0.f;
#pragma unroll 4
  for (int k = 0; k < 192; ++k) s += (float)c[k] * w[(long)k * 3072];
  if (kq) red[kq][nl] = s;
  __syncthreads();
  if (kq == 0) {
    s += red[1][nl] + red[2][nl] + red[3][nl];
    hh[(long)r * 3072 + n] = fmaxf(s + b1[n], 0.f);
  }
}

__global__ __launch_bounds__(64) void head2_k(const float* __restrict__ hh,
                                              const float* __restrict__ W2,
                                              const float* __restrict__ b2,
                                              float* __restrict__ out) {
  const int o = blockIdx.x;
  const int r = o / 7, n = o % 7;
  const int lane = threadIdx.x;
  const float* hr = hh + (long)r * 3072;
  float s = 0.f;
  for (int k = lane; k < 3072; k += 64) s += hr[k] * W2[(long)k * 7 + n];
#pragma unroll
  for (int off = 32; off > 0; off >>= 1) s += __shfl_xor(s, off);
  if (lane == 0) out[o] = s + b2[n];
}

// ---- driver --------------------------------------------------------------
extern "C" void kernel_launch(void* const* d_in, const int* in_sizes, int n_in,
                              void* d_out, int out_size, void* d_ws, size_t ws_size,
                              hipStream_t stream) {
  (void)in_sizes; (void)n_in; (void)out_size; (void)ws_size;
  const float* images   = (const float*)d_in[0];
  const float* goal_img = (const float*)d_in[1];
  const int*   txt      = (const int*)d_in[2];
  const float* patch_W  = (const float*)d_in[3];
  const float* patch_b  = (const float*)d_in[4];
  const float* tok_emb  = (const float*)d_in[5];
  const float* pos_emb  = (const float*)d_in[6];
  const float* cls_tok  = (const float*)d_in[7];
  const float* goal_tok = (const float*)d_in[8];
  const float* Wq   = (const float*)d_in[9];
  const float* Wk   = (const float*)d_in[10];
  const float* Wv   = (const float*)d_in[11];
  const float* Wo   = (const float*)d_in[12];
  const float* bo   = (const float*)d_in[13];
  const float* ln1g = (const float*)d_in[14];
  const float* ln1b = (const float*)d_in[15];
  const float* ln2g = (const float*)d_in[16];
  const float* ln2b = (const float*)d_in[17];
  const float* W1   = (const float*)d_in[18];
  const float* b1   = (const float*)d_in[19];
  const float* W2   = (const float*)d_in[20];
  const float* b2   = (const float*)d_in[21];
  const float* lnfg = (const float*)d_in[22];
  const float* lnfb = (const float*)d_in[23];
  const float* aW1  = (const float*)d_in[24];
  const float* ab1  = (const float*)d_in[25];
  const float* aW2  = (const float*)d_in[26];
  const float* ab2  = (const float*)d_in[27];

  char* base = (char*)d_ws;
  size_t off = 0;
  auto take = [&](size_t bytes) -> char* {
    char* p = base + off;
    off += (bytes + 255) & ~(size_t)255;
    return p;
  };
  float*  x     = (float*) take((size_t)13696 * 768 * 4);
  __bf16* xn    = (__bf16*)take((size_t)13696 * 768 * 2);
  __bf16* shard = (__bf16*)take((size_t)13696 * 3072 * 2);  // patches|qkv|hbuf
  __bf16* attb  = (__bf16*)take((size_t)13696 * 768 * 2);
  __bf16* vt    = (__bf16*)take((size_t)384 * 64 * 448 * 2);
  float*  hh    = (float*) take((size_t)32 * 3072 * 4);
  __bf16* wqkv  = (__bf16*)take((size_t)12 * 2304 * 768 * 2);
  __bf16* wot   = (__bf16*)take((size_t)12 * 768 * 768 * 2);
  __bf16* w1t   = (__bf16*)take((size_t)12 * 768 * 3072 * 2);
  __bf16* w2t   = (__bf16*)take((size_t)12 * 768 * 3072 * 2);
  __bf16* pwt   = (__bf16*)take((size_t)768 * 768 * 2);
  __bf16* qkv   = shard;
  __bf16* hbuf  = shard;
  __bf16* patches = shard;

  const dim3 tpb(32, 8);
  transpose_pack<<<dim3(24, 24, 1), tpb, 0, stream>>>(patch_W, pwt, 768, 768, 1, 0L, 0L);
  transpose_pack<<<dim3(2, 24, 144), tpb, 0, stream>>>(Wq, wqkv, 768, 64, 12, 1769472L, 49152L);
  transpose_pack<<<dim3(2, 24, 144), tpb, 0, stream>>>(Wk, wqkv + 589824, 768, 64, 12, 1769472L, 49152L);
  transpose_pack<<<dim3(2, 24, 144), tpb, 0, stream>>>(Wv, wqkv + 1179648, 768, 64, 12, 1769472L, 49152L);
  transpose_pack<<<dim3(24, 24, 12), tpb, 0, stream>>>(Wo, wot, 768, 768, 1, 589824L, 0L);
  transpose_pack<<<dim3(96, 24, 12), tpb, 0, stream>>>(W1, w1t, 768, 3072, 1, 2359296L, 0L);
  transpose_pack<<<dim3(24, 96, 12), tpb, 0, stream>>>(W2, w2t, 3072, 768, 1, 2359296L, 0L);

  patches_k<<<12544, 256, 0, stream>>>(images, goal_img, patches);
  assemble_k<<<1088, 256, 0, stream>>>(cls_tok, goal_tok, tok_emb, txt, pos_emb, x);
  // grids: 8 XCD-slots * rpx row-slots * nY cols (row-slots = ceil(nR/8))
  gemm256<3, 1><<<8 * 7 * 3, 512, 0, stream>>>(patches, pwt, 768, 768, 12544, 3,
                                               nullptr, x, patch_b, pos_emb);

  for (int l = 0; l < 12; ++l) {
    ln_k<0><<<13696, 64, 0, stream>>>(x, ln1g + l * 768, ln1b + l * 768, xn);
    gemm256<0, 1><<<8 * 7 * 9, 512, 0, stream>>>(xn, wqkv + (long)l * 1769472, 768, 2304,
                                                 13696, 9, qkv, nullptr, nullptr, nullptr);
    vtrans_k<<<dim3(384, 7), 256, 0, stream>>>(qkv, vt);
    attn_k<<<dim3(384, 7), 256, 0, stream>>>(qkv, vt, attb);
    gemm256<2, 1><<<8 * 7 * 3, 512, 0, stream>>>(attb, wot + (long)l * 589824, 768, 768,
                                                 13696, 3, nullptr, x, bo + l * 768, nullptr);
    ln_k<0><<<13696, 64, 0, stream>>>(x, ln2g + l * 768, ln2b + l * 768, xn);
    gemm256<1, 1><<<8 * 7 * 12, 512, 0, stream>>>(xn, w1t + (long)l * 2359296, 768, 3072,
                                                  13696, 12, hbuf, nullptr, b1 + l * 3072, nullptr);
    gemm256<2, 0><<<8 * 7 * 3, 512, 0, stream>>>(hbuf, w2t + (long)l * 2359296, 3072, 768,
                                                 13696, 3, nullptr, x, b2 + l * 768, nullptr);
  }
  // Final LN: only the 32 cls rows feed the action head.
  ln_k<1><<<32, 64, 0, stream>>>(x, lnfg, lnfb, xn);
  head1_k<<<1536, 256, 0, stream>>>(xn, aW1, ab1, hh);
  head2_k<<<224, 64, 0, stream>>>(hh, aW2, ab2, (float*)d_out);
}

// Round 4
// 5503.361 us; speedup vs baseline: 1.1186x; 1.0155x over previous
//
#include <hip/hip_runtime.h>
#include <hip/hip_bf16.h>
#include <cstdint>

typedef __bf16 bf16x8 __attribute__((ext_vector_type(8)));
typedef __bf16 bf16x4v __attribute__((ext_vector_type(4)));
typedef float f32x4 __attribute__((ext_vector_type(4)));

#define XROWS 13696L  // padded token-row count shared by all packed activations

// ---- MFMA + async-copy helpers -------------------------------------------
static __device__ __forceinline__ f32x4 mfma16(bf16x8 a, bf16x8 b, f32x4 c) {
  return __builtin_amdgcn_mfma_f32_16x16x32_bf16(a, b, c, 0, 0, 0);
}
static __device__ __forceinline__ void gld_lds16(const void* g, void* l) {
  __builtin_amdgcn_global_load_lds(
      (__attribute__((address_space(1))) void*)(uintptr_t)g,
      (__attribute__((address_space(3))) void*)l, 16, 0, 0);
}

// ---- GEMM 256x256, BK=32, 8 waves (2M x 4N), 4-deep LDS ring -------------
// C(MxN) = A(MxK) @ Bt(NxK)^T, bf16 in, fp32 accum.
// PACKA=1: A is K-panel-packed [p=k/32][row<XROWS][32] so each K-step's
//   A-tile is a contiguous 16KB stream per row-tile (DRAM page-friendly);
//   round-3 profiling showed the row-major A walk (64B per row @ 6KB pitch)
//   caps the A-stream at ~1 TB/s regardless of pipeline structure.
// Pipeline: compute buf[t%4] while staging buf[(t+3)%4]; one barrier/K-step;
// counted vmcnt(8) steady-state (never 0 mid-loop); setprio around MFMA.
// LDS swizzle: 16B chunk c of row r at pos c ^ ((r>>1)&3), applied on the
// global source (LDS dest is hardware-linear) and on fragment reads.
// EPI 0: bf16 row-major store; 1: bf16 relu(acc+bias) PACKED store;
// EPI 2: fp32 x += acc+bias; 3: patch embed remap + patch_b + pos_emb.
template <int EPI, int MODE, int PACKA>
__global__ __launch_bounds__(512, 2) void gemm256(
    const __bf16* __restrict__ A, const __bf16* __restrict__ Bt, int K, int ldc,
    int M, int nY,
    __bf16* __restrict__ outb, float* __restrict__ outf,
    const float* __restrict__ bias, const float* __restrict__ pos) {
  __shared__ __align__(16) __bf16 lds[4 * 16384];  // 4 bufs x (A 16KB | B 16KB)
  const int id = blockIdx.x;
  const int xcd = id & 7;
  const int j = id >> 3;
  const int rpx = (int)gridDim.x / (8 * nY);
  int bx, by;
  if (MODE == 0) { bx = xcd * rpx + j / nY; by = j % nY; }
  else           { by = j / rpx;            bx = xcd * rpx + j % rpx; }
  const long m0 = (long)bx * 256, n0 = (long)by * 256;
  if (m0 >= M) return;

  const int tid = threadIdx.x;
  const int wave = tid >> 6, lane = tid & 63;
  const int quad = lane >> 4, l16 = lane & 15;
  const int wm = wave >> 2, wn = wave & 3;  // 2x4 wave grid, 128x64 out each

  // staging: lane l of wave w -> LDS row w*16+(l>>2), chunk-pos l&3;
  // global chunk (l&3)^((l>>3)&3) so LDS pos p of row r holds chunk p^((r>>1)&3).
  const int gc = ((lane & 3) ^ ((lane >> 3) & 3)) * 8;
  const int srow = wave * 16 + (lane >> 2);
  const __bf16 *gA0, *gA1;
  long aStep;
  if (PACKA) {
    gA0 = A + (m0 + srow) * 32 + gc;
    gA1 = A + (m0 + 128 + srow) * 32 + gc;
    aStep = XROWS * 32;  // panel stride
  } else {
    gA0 = A + (m0 + srow) * (long)K + gc;
    gA1 = A + (m0 + 128 + srow) * (long)K + gc;
    aStep = 32;
  }
  const __bf16* gB0 = Bt + (n0 + srow) * (long)K + gc;
  const __bf16* gB1 = Bt + (n0 + 128 + srow) * (long)K + gc;
  const int ldw = wave * 1024;  // byte offset of this wave's 16-row slice

  // fragment reads: row stride 32 elems; chunk `quad` of row (base16+l16) is
  // at swizzled pos quad ^ ((l16>>1)&3).
  const int swz = (quad ^ ((l16 >> 1) & 3)) * 8;
  const int aoff = (wm * 128 + l16) * 32 + swz;        // + mf*512
  const int boff = 8192 + (wn * 64 + l16) * 32 + swz;  // + nf*512

  const f32x4 zz = {0.f, 0.f, 0.f, 0.f};
  f32x4 acc[8][4];
#pragma unroll
  for (int i = 0; i < 8; ++i)
#pragma unroll
    for (int jj = 0; jj < 4; ++jj) acc[i][jj] = zz;

  const int NT = K >> 5;  // K-steps of 32

  auto stage = [&](int tt) {
    char* bb = (char*)lds + (tt & 3) * 32768 + ldw;
    const long ka = (long)tt * aStep;
    const long kb = (long)tt * 32;
    gld_lds16(gA0 + ka, bb);
    gld_lds16(gA1 + ka, bb + 8192);
    gld_lds16(gB0 + kb, bb + 16384);
    gld_lds16(gB1 + kb, bb + 24576);
  };

  // prologue: stage tiles 0..2; ensure tile 0 resident (8 = 2 tiles in flight)
  stage(0); stage(1); stage(2);
  asm volatile("s_waitcnt vmcnt(8)\n\ts_barrier" ::: "memory");

  for (int t = 0; t < NT; ++t) {
    if (t + 3 < NT) stage(t + 3);
    const __bf16* bb = lds + (t & 3) * 16384;
    bf16x8 af[8], bf[4];
#pragma unroll
    for (int mf = 0; mf < 8; ++mf) af[mf] = *(const bf16x8*)(bb + aoff + mf * 512);
#pragma unroll
    for (int nf = 0; nf < 4; ++nf) bf[nf] = *(const bf16x8*)(bb + boff + nf * 512);
    __builtin_amdgcn_s_setprio(1);
#pragma unroll
    for (int mf = 0; mf < 8; ++mf)
#pragma unroll
      for (int nf = 0; nf < 4; ++nf)
        acc[mf][nf] = mfma16(af[mf], bf[nf], acc[mf][nf]);
    __builtin_amdgcn_s_setprio(0);
    if (t + 1 < NT) {
      // need tile t+1 resident past this barrier; leave newer tiles in flight
      if (t + 4 <= NT)      asm volatile("s_waitcnt vmcnt(8)\n\ts_barrier" ::: "memory");
      else if (t + 3 == NT) asm volatile("s_waitcnt vmcnt(4)\n\ts_barrier" ::: "memory");
      else                  asm volatile("s_waitcnt vmcnt(0)\n\ts_barrier" ::: "memory");
    }
  }

#pragma unroll
  for (int mf = 0; mf < 8; ++mf) {
#pragma unroll
    for (int r = 0; r < 4; ++r) {
      const long row = m0 + wm * 128 + mf * 16 + quad * 4 + r;
      if (row >= M) continue;
      if (EPI == 3) {
        const int rr = (int)row;
        const int gsel = rr >= 6272 ? 1 : 0;
        const int rm = rr - gsel * 6272;
        const int bb2 = rm / 196, pp = rm % 196;
        const int tpos = gsel ? (198 + pp) : (1 + pp);
        float* xr = outf + ((long)bb2 * 426 + tpos) * 768;
        const float* pr = pos + (long)tpos * 768;
#pragma unroll
        for (int nf = 0; nf < 4; ++nf) {
          const long col = n0 + wn * 64 + nf * 16 + l16;
          xr[col] = acc[mf][nf][r] + bias[col] + pr[col];
        }
      } else {
#pragma unroll
        for (int nf = 0; nf < 4; ++nf) {
          const long col = n0 + wn * 64 + nf * 16 + l16;
          const float v = acc[mf][nf][r];
          if (EPI == 0) outb[row * ldc + col] = (__bf16)v;
          else if (EPI == 1)  // packed relu store (consumed by PACKA GEMM)
            outb[((col >> 5) * XROWS + row) * 32 + (col & 31)] =
                (__bf16)fmaxf(v + bias[col], 0.f);
          else outf[row * ldc + col] += v + bias[col];
        }
      }
    }
  }
}

// ---- fp32 (K,N) -> bf16 (N,K) batched transpose-pack ---------------------
__global__ __launch_bounds__(256) void transpose_pack(
    const float* __restrict__ in, __bf16* __restrict__ out, int K, int N,
    int nh, long out_ls, long out_hs) {
  __shared__ float tile[32][33];
  const int z = blockIdx.z;
  const long in_o = (long)z * K * N;
  const long out_o = (long)(z / nh) * out_ls + (long)(z % nh) * out_hs;
  const int n0 = blockIdx.x * 32, k0 = blockIdx.y * 32;
  const int tx = threadIdx.x, ty = threadIdx.y;
#pragma unroll
  for (int i = 0; i < 4; ++i)
    tile[ty + i * 8][tx] = in[in_o + (long)(k0 + ty + i * 8) * N + n0 + tx];
  __syncthreads();
#pragma unroll
  for (int i = 0; i < 4; ++i)
    out[out_o + (long)(n0 + ty + i * 8) * K + k0 + tx] = (__bf16)tile[tx][ty + i * 8];
}

// ---- patch extraction: images -> bf16 patch matrix (12544 x 768) ---------
__global__ __launch_bounds__(256) void patches_k(const float* __restrict__ img0,
                                                 const float* __restrict__ img1,
                                                 __bf16* __restrict__ out) {
  const int row = blockIdx.x;
  const int gsel = row >= 6272 ? 1 : 0;
  const int rm = row - gsel * 6272;
  const int b = rm / 196, p = rm % 196;
  const int py = p / 14, px = p % 14;
  const float* img = gsel ? img1 : img0;
#pragma unroll
  for (int i = 0; i < 3; ++i) {
    const int k = threadIdx.x + i * 256;
    const int pidx = k / 3, c = k - pidx * 3;
    const int pr = pidx >> 4, pc = pidx & 15;
    const float v = img[(((long)b * 224 + py * 16 + pr) * 224 + px * 16 + pc) * 3 + c];
    out[(long)row * 768 + k] = (__bf16)v;
  }
}

// ---- cls/goal/lang token rows + pos_emb into fp32 x ----------------------
__global__ __launch_bounds__(256) void assemble_k(
    const float* __restrict__ cls_tok, const float* __restrict__ goal_tok,
    const float* __restrict__ tok_emb, const int* __restrict__ txt,
    const float* __restrict__ pos, float* __restrict__ x) {
  const int z = blockIdx.x;
  const int b = z / 34, j = z % 34;
  const int t = (j == 0) ? 0 : (j == 1) ? 197 : (392 + j);
  const float* src = (j == 0) ? cls_tok
                   : (j == 1) ? goal_tok
                              : tok_emb + (long)txt[b * 32 + (j - 2)] * 768;
  float* dst = x + ((long)b * 426 + t) * 768;
  const float* pr = pos + (long)t * 768;
#pragma unroll
  for (int i = 0; i < 3; ++i) {
    const int k = threadIdx.x + i * 256;
    dst[k] = src[k] + pr[k];
  }
}

// ---- LayerNorm fp32 -> bf16 (one wave per row) ---------------------------
// CLS=0: output K-panel-packed [e/32][row][32] (feeds PACKA GEMMs).
// CLS=1: gather cls rows (blockIdx.x*426) -> compact row-major 32x768.
template <int CLS>
__global__ __launch_bounds__(64) void ln_k(const float* __restrict__ x,
                                           const float* __restrict__ g,
                                           const float* __restrict__ b,
                                           __bf16* __restrict__ out) {
  const int row = blockIdx.x, lane = threadIdx.x;
  const long irow = CLS ? (long)row * 426 : (long)row;
  const float4* xr = (const float4*)(x + irow * 768);
  float4 v[3];
  float s = 0.f, q = 0.f;
#pragma unroll
  for (int i = 0; i < 3; ++i) {
    v[i] = xr[lane + i * 64];
    s += v[i].x + v[i].y + v[i].z + v[i].w;
    q += v[i].x * v[i].x + v[i].y * v[i].y + v[i].z * v[i].z + v[i].w * v[i].w;
  }
#pragma unroll
  for (int o = 32; o > 0; o >>= 1) {
    s += __shfl_xor(s, o);
    q += __shfl_xor(q, o);
  }
  const float mean = s * (1.f / 768.f);
  const float var = q * (1.f / 768.f) - mean * mean;
  const float rs = rsqrtf(var + 1e-5f);
  const float4* g4 = (const float4*)g;
  const float4* b4 = (const float4*)b;
#pragma unroll
  for (int i = 0; i < 3; ++i) {
    const float4 gg = g4[lane + i * 64], bb = b4[lane + i * 64];
    bf16x4v o4;
    o4[0] = (__bf16)((v[i].x - mean) * rs * gg.x + bb.x);
    o4[1] = (__bf16)((v[i].y - mean) * rs * gg.y + bb.y);
    o4[2] = (__bf16)((v[i].z - mean) * rs * gg.z + bb.z);
    o4[3] = (__bf16)((v[i].w - mean) * rs * gg.w + bb.w);
    const int e0 = (lane + i * 64) * 4;
    if (CLS)
      *(bf16x4v*)(out + (long)row * 768 + e0) = o4;
    else
      *(bf16x4v*)(out + ((long)(e0 >> 5) * XROWS + row) * 32 + (e0 & 31)) = o4;
  }
}

// ---- V transpose per head: qkv[:,1536+h*64+e] -> vt[bh][e][448] ----------
__global__ __launch_bounds__(256) void vtrans_k(const __bf16* __restrict__ qkv,
                                                __bf16* __restrict__ vt) {
  __shared__ __bf16 tile[64][66];
  const int bh = blockIdx.x;
  const int b = bh / 12, h = bh % 12;
  const int s0 = blockIdx.y * 64;
  const int t = threadIdx.x;
  const int sr = t >> 2, part = t & 3;
  const __bf16* src = qkv + ((long)(b * 426 + s0 + sr)) * 2304 + 1536 + h * 64 + part * 16;
#pragma unroll
  for (int j = 0; j < 16; ++j) tile[sr][part * 16 + j] = src[j];
  __syncthreads();
  __bf16* dst = vt + ((long)bh * 64 + sr) * 448 + s0 + part * 16;
#pragma unroll
  for (int j = 0; j < 16; ++j) {
    const int s = s0 + part * 16 + j;
    dst[j] = (s < 426) ? tile[part * 16 + j][sr] : (__bf16)0.f;
  }
}

// ---- flash attention: 4 waves/WG, 64-query tile, 64-key chunks -----------
// Output attb is K-panel-packed (feeds PACKA wo-GEMM).
__global__ __launch_bounds__(256) void attn_k(const __bf16* __restrict__ qkv,
                                              const __bf16* __restrict__ vt,
                                              __bf16* __restrict__ attout) {
  __shared__ __align__(16) __bf16 lds[8192 + 4096];  // K(4096) | V(4096) | P(4096)
  const int tid = threadIdx.x;
  const int wave = tid >> 6, lane = tid & 63;
  const int quad = lane >> 4, l16 = lane & 15;
  const int bh = blockIdx.x;
  const int b = bh / 12, h = bh % 12;
  const int q0 = blockIdx.y * 64 + wave * 16;
  const long b426 = (long)b * 426;

  const int swz0 = ((quad) ^ (l16 & 7)) * 8;
  const int swz1 = ((4 + quad) ^ (l16 & 7)) * 8;
  __bf16* lsK = lds;
  __bf16* lsV = lds + 4096;
  __bf16* lsP = lds + 8192 + wave * 1024;

  const __bf16* gsrc[4];
  long gstep[4];
#pragma unroll
  for (int s = 0; s < 4; ++s) {
    const int c = s * 256 + tid;
    if (c < 512) {
      const int key = c >> 3, part = (c & 7) ^ (key & 7);
      gsrc[s] = qkv + (b426 + key) * 2304 + 768 + h * 64 + part * 8;
      gstep[s] = 64 * 2304;
    } else {
      const int cv = c - 512;
      const int e = cv >> 3, part = (cv & 7) ^ (e & 7);
      gsrc[s] = vt + ((long)bh * 64 + e) * 448 + part * 8;
      gstep[s] = 64;
    }
  }
  __bf16* ldst[4];
#pragma unroll
  for (int s = 0; s < 4; ++s) ldst[s] = lds + (s * 256 + (tid & ~63)) * 8;

  const long qrow = (b426 + q0 + l16) * 2304 + h * 64;
  const bf16x8 aq0 = *(const bf16x8*)(qkv + qrow + quad * 8);
  const bf16x8 aq1 = *(const bf16x8*)(qkv + qrow + 32 + quad * 8);

  const f32x4 zz = {0.f, 0.f, 0.f, 0.f};
  f32x4 o[4] = {zz, zz, zz, zz};
  float m_i[4] = {-3e38f, -3e38f, -3e38f, -3e38f};
  float l_i[4] = {0.f, 0.f, 0.f, 0.f};
  const float scale = 0.03608439182435161f;  // 768^-0.5

  for (int kc = 0; kc < 7; ++kc) {
    const int kbase = kc * 64;
    __syncthreads();
#pragma unroll
    for (int s = 0; s < 4; ++s) {
      gld_lds16(gsrc[s], ldst[s]);
      gsrc[s] += gstep[s];
    }
    __syncthreads();

    f32x4 s4[4] = {zz, zz, zz, zz};
#pragma unroll
    for (int nt = 0; nt < 4; ++nt) {
      const __bf16* kb = lsK + (nt * 16 + l16) * 64;
      s4[nt] = mfma16(aq0, *(const bf16x8*)(kb + swz0), s4[nt]);
      s4[nt] = mfma16(aq1, *(const bf16x8*)(kb + swz1), s4[nt]);
    }

    const int lim = 426 - kbase - l16;
#pragma unroll
    for (int r = 0; r < 4; ++r) {
      float a0 = (0 < lim)  ? s4[0][r] * scale : -1e30f;
      float a1 = (16 < lim) ? s4[1][r] * scale : -1e30f;
      float a2 = (32 < lim) ? s4[2][r] * scale : -1e30f;
      float a3 = (48 < lim) ? s4[3][r] * scale : -1e30f;
      float mx = fmaxf(fmaxf(a0, a1), fmaxf(a2, a3));
#pragma unroll
      for (int w = 1; w < 16; w <<= 1) mx = fmaxf(mx, __shfl_xor(mx, w, 16));
      mx = fmaxf(mx, m_i[r]);
      const float alpha = __expf(m_i[r] - mx);
      m_i[r] = mx;
      const float p0 = __expf(a0 - mx), p1 = __expf(a1 - mx);
      const float p2 = __expf(a2 - mx), p3 = __expf(a3 - mx);
      float rs = (p0 + p1) + (p2 + p3);
#pragma unroll
      for (int w = 1; w < 16; w <<= 1) rs += __shfl_xor(rs, w, 16);
      l_i[r] = l_i[r] * alpha + rs;
      o[0][r] *= alpha; o[1][r] *= alpha; o[2][r] *= alpha; o[3][r] *= alpha;
      const int rowb = quad * 4 + r;
      __bf16* pb = lsP + rowb * 64 + (l16 & 7);
      const int l8 = l16 >> 3, rx = rowb & 7;
      pb[((0 + l8) ^ rx) * 8] = (__bf16)p0;
      pb[((2 + l8) ^ rx) * 8] = (__bf16)p1;
      pb[((4 + l8) ^ rx) * 8] = (__bf16)p2;
      pb[((6 + l8) ^ rx) * 8] = (__bf16)p3;
    }

    const bf16x8 pa0 = *(const bf16x8*)(lsP + l16 * 64 + swz0);
    const bf16x8 pa1 = *(const bf16x8*)(lsP + l16 * 64 + swz1);
#pragma unroll
    for (int et = 0; et < 4; ++et) {
      const __bf16* vb = lsV + (et * 16 + l16) * 64;
      o[et] = mfma16(pa0, *(const bf16x8*)(vb + swz0), o[et]);
      o[et] = mfma16(pa1, *(const bf16x8*)(vb + swz1), o[et]);
    }
  }

#pragma unroll
  for (int r = 0; r < 4; ++r) {
    const int q = q0 + quad * 4 + r;
    if (q < 426) {
      const float inv = 1.f / l_i[r];
      const long row = b426 + q;
#pragma unroll
      for (int et = 0; et < 4; ++et) {
        const int col = h * 64 + et * 16 + l16;
        attout[((long)(col >> 5) * XROWS + row) * 32 + (col & 31)] =
            (__bf16)(o[et][r] * inv);
      }
    }
  }
}

// ---- action head ---------------------------------------------------------
__global__ __launch_bounds__(256) void head1_k(const __bf16* __restrict__ cls,
                                               const float* __restrict__ W1,
                                               const float* __restrict__ b1,
                                               float* __restrict__ hh) {
  __shared__ float red[4][64];
  const int blk = blockIdx.x;
  const int r = blk / 48, nt = blk % 48;
  const int tid = threadIdx.x;
  const int kq = tid >> 6, nl = tid & 63;
  const int n = nt * 64 + nl;
  const __bf16* c = cls + (long)r * 768 + kq * 192;
  const float* w = W1 + (long)(kq * 192) * 3072 + n;
  float s = 0.f;
#pragma unroll 4
  for (int k = 0; k < 192; ++k) s += (float)c[k] * w[(long)k * 3072];
  if (kq) red[kq][nl] = s;
  __syncthreads();
  if (kq == 0) {
    s += red[1][nl] + red[2][nl] + red[3][nl];
    hh[(long)r * 3072 + n] = fmaxf(s + b1[n], 0.f);
  }
}

__global__ __launch_bounds__(64) void head2_k(const float* __restrict__ hh,
                                              const float* __restrict__ W2,
                                              const float* __restrict__ b2,
                                              float* __restrict__ out) {
  const int o = blockIdx.x;
  const int r = o / 7, n = o % 7;
  const int lane = threadIdx.x;
  const float* hr = hh + (long)r * 3072;
  float s = 0.f;
  for (int k = lane; k < 3072; k += 64) s += hr[k] * W2[(long)k * 7 + n];
#pragma unroll
  for (int off = 32; off > 0; off >>= 1) s += __shfl_xor(s, off);
  if (lane == 0) out[o] = s + b2[n];
}

// ---- driver --------------------------------------------------------------
extern "C" void kernel_launch(void* const* d_in, const int* in_sizes, int n_in,
                              void* d_out, int out_size, void* d_ws, size_t ws_size,
                              hipStream_t stream) {
  (void)in_sizes; (void)n_in; (void)out_size; (void)ws_size;
  const float* images   = (const float*)d_in[0];
  const float* goal_img = (const float*)d_in[1];
  const int*   txt      = (const int*)d_in[2];
  const float* patch_W  = (const float*)d_in[3];
  const float* patch_b  = (const float*)d_in[4];
  const float* tok_emb  = (const float*)d_in[5];
  const float* pos_emb  = (const float*)d_in[6];
  const float* cls_tok  = (const float*)d_in[7];
  const float* goal_tok = (const float*)d_in[8];
  const float* Wq   = (const float*)d_in[9];
  const float* Wk   = (const float*)d_in[10];
  const float* Wv   = (const float*)d_in[11];
  const float* Wo   = (const float*)d_in[12];
  const float* bo   = (const float*)d_in[13];
  const float* ln1g = (const float*)d_in[14];
  const float* ln1b = (const float*)d_in[15];
  const float* ln2g = (const float*)d_in[16];
  const float* ln2b = (const float*)d_in[17];
  const float* W1   = (const float*)d_in[18];
  const float* b1   = (const float*)d_in[19];
  const float* W2   = (const float*)d_in[20];
  const float* b2   = (const float*)d_in[21];
  const float* lnfg = (const float*)d_in[22];
  const float* lnfb = (const float*)d_in[23];
  const float* aW1  = (const float*)d_in[24];
  const float* ab1  = (const float*)d_in[25];
  const float* aW2  = (const float*)d_in[26];
  const float* ab2  = (const float*)d_in[27];

  char* base = (char*)d_ws;
  size_t off = 0;
  auto take = [&](size_t bytes) -> char* {
    char* p = base + off;
    off += (bytes + 255) & ~(size_t)255;
    return p;
  };
  float*  x     = (float*) take((size_t)13696 * 768 * 4);
  __bf16* xn    = (__bf16*)take((size_t)13696 * 768 * 2);   // packed [24][13696][32]
  __bf16* shard = (__bf16*)take((size_t)13696 * 3072 * 2);  // patches|qkv|hbuf
  __bf16* attb  = (__bf16*)take((size_t)13696 * 768 * 2);   // packed [24][13696][32]
  __bf16* vt    = (__bf16*)take((size_t)384 * 64 * 448 * 2);
  __bf16* xcls  = (__bf16*)take((size_t)32 * 768 * 2);
  float*  hh    = (float*) take((size_t)32 * 3072 * 4);
  __bf16* wqkv  = (__bf16*)take((size_t)12 * 2304 * 768 * 2);
  __bf16* wot   = (__bf16*)take((size_t)12 * 768 * 768 * 2);
  __bf16* w1t   = (__bf16*)take((size_t)12 * 768 * 3072 * 2);
  __bf16* w2t   = (__bf16*)take((size_t)12 * 768 * 3072 * 2);
  __bf16* pwt   = (__bf16*)take((size_t)768 * 768 * 2);
  __bf16* qkv   = shard;          // row-major ldc=2304
  __bf16* hbuf  = shard;          // packed [96][13696][32]
  __bf16* patches = shard;        // row-major 12544x768

  const dim3 tpb(32, 8);
  transpose_pack<<<dim3(24, 24, 1), tpb, 0, stream>>>(patch_W, pwt, 768, 768, 1, 0L, 0L);
  transpose_pack<<<dim3(2, 24, 144), tpb, 0, stream>>>(Wq, wqkv, 768, 64, 12, 1769472L, 49152L);
  transpose_pack<<<dim3(2, 24, 144), tpb, 0, stream>>>(Wk, wqkv + 589824, 768, 64, 12, 1769472L, 49152L);
  transpose_pack<<<dim3(2, 24, 144), tpb, 0, stream>>>(Wv, wqkv + 1179648, 768, 64, 12, 1769472L, 49152L);
  transpose_pack<<<dim3(24, 24, 12), tpb, 0, stream>>>(Wo, wot, 768, 768, 1, 589824L, 0L);
  transpose_pack<<<dim3(96, 24, 12), tpb, 0, stream>>>(W1, w1t, 768, 3072, 1, 2359296L, 0L);
  transpose_pack<<<dim3(24, 96, 12), tpb, 0, stream>>>(W2, w2t, 3072, 768, 1, 2359296L, 0L);

  patches_k<<<12544, 256, 0, stream>>>(images, goal_img, patches);
  assemble_k<<<1088, 256, 0, stream>>>(cls_tok, goal_tok, tok_emb, txt, pos_emb, x);
  // grids: 8 XCD-slots * rpx row-slots * nY cols (row-slots = ceil(nR/8))
  gemm256<3, 1, 0><<<8 * 7 * 3, 512, 0, stream>>>(patches, pwt, 768, 768, 12544, 3,
                                                  nullptr, x, patch_b, pos_emb);

  for (int l = 0; l < 12; ++l) {
    ln_k<0><<<13696, 64, 0, stream>>>(x, ln1g + l * 768, ln1b + l * 768, xn);
    gemm256<0, 1, 1><<<8 * 7 * 9, 512, 0, stream>>>(xn, wqkv + (long)l * 1769472, 768, 2304,
                                                    13696, 9, qkv, nullptr, nullptr, nullptr);
    vtrans_k<<<dim3(384, 7), 256, 0, stream>>>(qkv, vt);
    attn_k<<<dim3(384, 7), 256, 0, stream>>>(qkv, vt, attb);
    gemm256<2, 1, 1><<<8 * 7 * 3, 512, 0, stream>>>(attb, wot + (long)l * 589824, 768, 768,
                                                    13696, 3, nullptr, x, bo + l * 768, nullptr);
    ln_k<0><<<13696, 64, 0, stream>>>(x, ln2g + l * 768, ln2b + l * 768, xn);
    gemm256<1, 1, 1><<<8 * 7 * 12, 512, 0, stream>>>(xn, w1t + (long)l * 2359296, 768, 3072,
                                                     13696, 12, hbuf, nullptr, b1 + l * 3072, nullptr);
    gemm256<2, 0, 1><<<8 * 7 * 3, 512, 0, stream>>>(hbuf, w2t + (long)l * 2359296, 3072, 768,
                                                    13696, 3, nullptr, x, b2 + l * 768, nullptr);
  }
  // Final LN: only the 32 cls rows feed the action head (compact row-major).
  ln_k<1><<<32, 64, 0, stream>>>(x, lnfg, lnfb, xcls);
  head1_k<<<1536, 256, 0, stream>>>(xcls, aW1, ab1, hh);
  head2_k<<<224, 64, 0, stream>>>(hh, aW2, ab2, (float*)d_out);
}